// Round 11
// baseline (98.836 us; speedup 1.0000x reference)
//
#include <hip/hip_runtime.h>
#include <hip/hip_bf16.h>

// ---------------------------------------------------------------------------
// Model: [conv1+conv2 fused, MFMA] -> fcc(MFMA, barrier-free direct-load) ->
//        reduce(full-chip) -> head(gcn+fcg+MLP)
// B=64, K(nodes)=128, N_BAND=5, HW=128, CH=16
// ---------------------------------------------------------------------------

#define IMG     16384     // 128*128
#define FCC_K   262144    // 16*128*128
#define FCC_BLOCKS 1024
#define FCC_KRANGE 256    // FCC_K / FCC_BLOCKS

typedef __attribute__((ext_vector_type(8))) short bf16x8;
typedef __attribute__((ext_vector_type(4))) float f32x4;
typedef __attribute__((ext_vector_type(4))) unsigned short us4;
typedef __attribute__((ext_vector_type(8))) unsigned short us8;
typedef __attribute__((ext_vector_type(4))) unsigned int u32x4;

// RNE float->bf16 bits (finite inputs only)
__device__ __forceinline__ unsigned short f2bf(float f) {
    unsigned u = __float_as_uint(f);
    unsigned r = (u + 0x7FFFu + ((u >> 16) & 1u)) >> 16;
    return (unsigned short)r;
}
__device__ __forceinline__ float bf2f(unsigned short b) {
    unsigned u = ((unsigned)b) << 16;
    return __uint_as_float(u);
}
// round-half-up bf16 pair pack: a -> low half, b -> high half.
// |err| <= 0.5ulp + 2^-17 (ties round up instead of to-even; negligible).
__device__ __forceinline__ unsigned pack2bf(float a, float b) {
    unsigned ua = __float_as_uint(a) + 0x8000u;
    unsigned ub = __float_as_uint(b) + 0x8000u;
    return (ua >> 16) | (ub & 0xFFFF0000u);
}

// ---------------------------------------------------------------------------
// Kernel 1: fused conv1+conv2 (3x3 SAME, relu both) -> bf16 c2. (R8 proven)
// ---------------------------------------------------------------------------
__global__ __launch_bounds__(256) void conv12_kernel(
    const float* __restrict__ x2,     // (64,128,128)
    const float* __restrict__ w1,     // (16,1,3,3)
    const float* __restrict__ b1,     // (16)
    const float* __restrict__ w2,     // (16,16,3,3)
    const float* __restrict__ b2,     // (16)
    unsigned short* __restrict__ c2bf)// (64,16,128,128) bf16
{
    __shared__ float sx2[8][130];
    __shared__ unsigned short sin[6*130*16];
    __shared__ unsigned short sB[5*512];
    __shared__ float sw1[144], sb1v[16];

    int tid = threadIdx.x;
    int blk = blockIdx.x;                     // 64 images * 32 row-groups
    int b   = blk >> 5;
    int R0  = (blk & 31) * 4;

    if (tid < 144) sw1[tid] = w1[tid];
    if (tid < 16)  sb1v[tid] = b1[tid];

    for (int idx = tid; idx < 2560; idx += 256) {
        int q   = idx >> 9;
        int rem = idx & 511;
        int l   = rem >> 3;
        int e   = rem & 7;
        int k   = (l >> 4) * 8 + e;
        int oc  = l & 15;
        int ic  = k & 15;
        int dd  = 2*q + (k >> 4);
        unsigned short bits = 0;
        if (dd < 9) bits = f2bf(w2[oc*144 + ic*9 + dd]);
        sB[idx] = bits;
    }
    if (tid < 192) {
        int rr = tid >> 5, rem = tid & 31;
        int cc = (rem < 16) ? 0 : 129;
        sin[(rr*130 + cc)*16 + (rem & 15)] = 0;
    }
    {
        const float* xb = x2 + (size_t)b * IMG;
        for (int idx = tid; idx < 8*130; idx += 256) {
            int rr = idx / 130, cc = idx - rr*130;
            int ri = R0 - 2 + rr, gj = cc - 1;
            float v = 0.f;
            if (ri >= 0 && ri < 128 && gj >= 0 && gj < 128)
                v = xb[ri*128 + gj];
            sx2[rr][cc] = v;
        }
    }
    __syncthreads();

    for (int p = tid; p < 768; p += 256) {
        int rr = p >> 7;
        int cc = p & 127;
        int ri1 = R0 - 1 + rr;
        bool valid = (ri1 >= 0 && ri1 < 128);
        float in9[3][3];
        #pragma unroll
        for (int di = 0; di < 3; ++di)
          #pragma unroll
          for (int dj = 0; dj < 3; ++dj)
              in9[di][dj] = sx2[rr + di][cc + dj];
        us8 o0, o1;
        #pragma unroll
        for (int oc = 0; oc < 16; ++oc) {
            float acc = sb1v[oc];
            #pragma unroll
            for (int di = 0; di < 3; ++di)
              #pragma unroll
              for (int dj = 0; dj < 3; ++dj)
                  acc += in9[di][dj] * sw1[oc*9 + di*3 + dj];
            unsigned short bits = valid ? f2bf(fmaxf(acc, 0.f)) : (unsigned short)0;
            if (oc < 8) o0[oc] = bits; else o1[oc - 8] = bits;
        }
        unsigned short* dst = &sin[(rr*130 + cc + 1)*16];
        *reinterpret_cast<us8*>(dst)     = o0;
        *reinterpret_cast<us8*>(dst + 8) = o1;
    }
    __syncthreads();

    int lane = tid & 63;
    int wv   = tid >> 6;
    int ln   = lane & 15;
    int g    = lane >> 4;
    int ghalf = g & 1;

    int aoff[5];
    #pragma unroll
    for (int q = 0; q < 5; ++q) {
        int dd = 2*q + (g >> 1);
        if (dd > 8) dd = 8;
        int di = dd / 3, dj = dd % 3;
        aoff[q] = ((wv + di)*130 + ln + dj)*16 + ghalf*8;
    }

    bf16x8 bf[5];
    #pragma unroll
    for (int q = 0; q < 5; ++q)
        bf[q] = *reinterpret_cast<const bf16x8*>(&sB[q*512 + lane*8]);

    float bias_oc = b2[ln];
    int r = R0 + wv;
    unsigned short* outbase = c2bf + ((size_t)b*16 + ln)*IMG + r*128;

    #pragma unroll
    for (int t = 0; t < 8; ++t) {
        f32x4 acc = {0.f, 0.f, 0.f, 0.f};
        #pragma unroll
        for (int q = 0; q < 5; ++q) {
            bf16x8 a = *reinterpret_cast<const bf16x8*>(&sin[aoff[q] + t*256]);
            acc = __builtin_amdgcn_mfma_f32_16x16x32_bf16(a, bf[q], acc, 0, 0, 0);
        }
        int pc = t*16 + g*4;
        us4 pk;
        #pragma unroll
        for (int reg = 0; reg < 4; ++reg)
            pk[reg] = f2bf(fmaxf(acc[reg] + bias_oc, 0.f));
        *reinterpret_cast<us4*>(&outbase[pc]) = pk;
    }
}

// ---------------------------------------------------------------------------
// Kernel 2: fcc split-K partials, bf16 MFMA — BARRIER-FREE direct-load.
// No LDS, no __syncthreads: each lane loads its B-fragment (8 dwords of one
// W column, stride 512B) straight from global; all 64 loads of a k-step fold
// into offset:N off one base. B addresses are wave-invariant across the
// block's 4 waves -> L1 serves the 4x re-read. With no barriers the compiler
// emits counted vmcnt and pipelines loads across MFMAs -> W-stream never
// drains (the vmcnt(0)-before-s_barrier drain was the ~2.3 TB/s cap).
// ---------------------------------------------------------------------------
__global__ __launch_bounds__(256, 4) void fcc_mfma(
    const unsigned short* __restrict__ c2bf, // (64, 262144) bf16 row-major
    const float* __restrict__ W,             // (262144, 128) fp32
    unsigned short* __restrict__ partials)   // (1024, 64*128) bf16
{
    int tid  = threadIdx.x;
    int blk  = blockIdx.x;
    int k0   = blk * FCC_KRANGE;
    int lane = tid & 63, wv = tid >> 6;
    int ln   = lane & 15, g = lane >> 4;

    f32x4 acc[8];
    #pragma unroll
    for (int j = 0; j < 8; ++j) acc[j] = (f32x4){0.f,0.f,0.f,0.f};

    const unsigned short* arow = c2bf + (size_t)(16*wv + ln)*FCC_K + k0 + g*8;

    for (int ks = 0; ks < 8; ++ks) {
        bf16x8 af = *reinterpret_cast<const bf16x8*>(arow + ks*32);
        // per-lane base: row (k0+ks*32+g*8), column ln
        const float* Wk = W + (size_t)(k0 + ks*32 + g*8)*128 + ln;
        #pragma unroll
        for (int j = 0; j < 8; ++j) {
            const float* Wj = Wk + j*16;      // col = j*16 + ln
            float w0 = Wj[0*128], w1 = Wj[1*128];
            float w2 = Wj[2*128], w3 = Wj[3*128];
            float w4 = Wj[4*128], w5 = Wj[5*128];
            float w6 = Wj[6*128], w7 = Wj[7*128];
            u32x4 pk;
            pk[0] = pack2bf(w0, w1);
            pk[1] = pack2bf(w2, w3);
            pk[2] = pack2bf(w4, w5);
            pk[3] = pack2bf(w6, w7);
            bf16x8 bfrag = *reinterpret_cast<bf16x8*>(&pk);
            acc[j] = __builtin_amdgcn_mfma_f32_16x16x32_bf16(af, bfrag, acc[j], 0, 0, 0);
        }
    }

    unsigned short* p = partials + (size_t)blk * 8192;
    #pragma unroll
    for (int j = 0; j < 8; ++j)
      #pragma unroll
      for (int reg = 0; reg < 4; ++reg) {
          int m = 16*wv + g*4 + reg;
          p[m*128 + j*16 + ln] = f2bf(acc[j][reg]);
      }
}

// ---------------------------------------------------------------------------
// Kernel 3: full-chip reduce of bf16 partials -> cvec = relu(sum + bias).
// 256 blocks x 256 thr; block handles 32 outputs, 8-way K-split.
// ---------------------------------------------------------------------------
__global__ __launch_bounds__(256) void fcc_reduce(
    const unsigned short* __restrict__ partials, // (1024, 8192) bf16
    const float* __restrict__ bias,              // (128)
    float* __restrict__ cvec)                    // (64,128)
{
    __shared__ float sred[8][32];
    int blk = blockIdx.x, t = threadIdx.x;
    int o  = blk*32 + (t & 31);
    int pr = t >> 5;                 // 0..7
    const unsigned short* pb = partials + (size_t)pr*8192 + o;
    float s = 0.f;
    #pragma unroll 16
    for (int i = 0; i < FCC_BLOCKS/8; ++i)
        s += bf2f(pb[(size_t)i*8*8192]);
    sred[pr][t & 31] = s;
    __syncthreads();
    if (t < 32) {
        float v = 0.f;
        #pragma unroll
        for (int p2 = 0; p2 < 8; ++p2) v += sred[p2][t];
        cvec[o] = fmaxf(v + bias[o & 127], 0.f);
    }
}

// ---------------------------------------------------------------------------
// Kernel 4: head — gcn chain + fcg + MLP from cvec. 64 blocks x 128.
// ---------------------------------------------------------------------------
__global__ __launch_bounds__(128) void head_kernel(
    const float* __restrict__ cvec,     // (64,128)
    const float* __restrict__ x1,       // (8192,5)
    const float* __restrict__ gW1, const float* __restrict__ gb1,
    const float* __restrict__ gW2, const float* __restrict__ gb2,
    const float* __restrict__ fcgW, const float* __restrict__ fcgb,
    const float* __restrict__ w1, const float* __restrict__ bb1,
    const float* __restrict__ w2, const float* __restrict__ bb2,
    const float* __restrict__ w3, const float* __restrict__ bb3,
    float* __restrict__ out)
{
    __shared__ float sx[256], sh[128], s2[64], sh2[128];
    __shared__ float sW1[50], sb1s[10], sW2s[10], smean[10];
    __shared__ float sy1[128][10];
    int b = blockIdx.x, t = threadIdx.x;

    if (t < 50) sW1[t] = gW1[t];
    if (t >= 64 && t < 74) { sb1s[t-64] = gb1[t-64]; sW2s[t-64] = gW2[t-64]; }
    sx[t] = cvec[b*128 + t];
    __syncthreads();

    float y[10];
    {
        int r = b*128 + t;
        float x[5];
        #pragma unroll
        for (int f = 0; f < 5; ++f) x[f] = x1[r*5 + f];
        #pragma unroll
        for (int oo = 0; oo < 10; ++oo) {
            float a = 0.f;
            #pragma unroll
            for (int f = 0; f < 5; ++f) a += x[f] * sW1[f*10 + oo];
            y[oo] = a;
        }
    }
    if (b == 0) {                    // block-uniform branch, barriers legal
        #pragma unroll
        for (int oo = 0; oo < 10; ++oo) sy1[t][oo] = y[oo];
        __syncthreads();
        if (t < 10) {
            float s = 0.f;
            for (int rr = 0; rr < 128; ++rr) s += sy1[rr][t];
            smean[t] = fmaxf(s * (1.f/128.f) + sb1s[t], 0.f);
        }
        __syncthreads();
    }
    {
        float h1row[10];
        if (b == 0) {
            #pragma unroll
            for (int oo = 0; oo < 10; ++oo) h1row[oo] = smean[oo];
        } else {
            #pragma unroll
            for (int oo = 0; oo < 10; ++oo) h1row[oo] = fmaxf(y[oo] + sb1s[oo], 0.f);
        }
        float y2 = 0.f;
        #pragma unroll
        for (int oo = 0; oo < 10; ++oo) y2 += h1row[oo] * sW2s[oo];
        sh2[t] = fmaxf(y2 + gb2[0], 0.f);
    }
    __syncthreads();

    {
        float acc = fcgb[t];
        #pragma unroll 8
        for (int k = 0; k < 128; ++k) acc += sh2[k] * fcgW[k*128 + t];
        sx[128 + t] = fmaxf(acc, 0.f);
    }
    __syncthreads();

    {
        float acc = bb1[t];
        for (int k = 0; k < 256; ++k) acc += sx[k] * w1[k*128 + t];
        sh[t] = fmaxf(acc, 0.f);
    }
    __syncthreads();
    if (t < 64) {
        float acc = bb2[t];
        for (int k = 0; k < 128; ++k) acc += sh[k] * w2[k*64 + t];
        s2[t] = fmaxf(acc, 0.f);
    }
    __syncthreads();
    if (t < 2) {
        float acc = bb3[t];
        for (int k = 0; k < 64; ++k) acc += s2[k] * w3[k*2 + t];
        out[b*2 + t] = 1.f / (1.f + __expf(-acc));
    }
}

// ---------------------------------------------------------------------------
extern "C" void kernel_launch(void* const* d_in, const int* in_sizes, int n_in,
                              void* d_out, int out_size, void* d_ws, size_t ws_size,
                              hipStream_t stream)
{
    const float* x1      = (const float*)d_in[0];
    const float* x2      = (const float*)d_in[1];
    const float* gcn1_w  = (const float*)d_in[2];
    const float* gcn1_b  = (const float*)d_in[3];
    const float* gcn2_w  = (const float*)d_in[4];
    const float* gcn2_b  = (const float*)d_in[5];
    const float* fcg_w   = (const float*)d_in[6];
    const float* fcg_b   = (const float*)d_in[7];
    const float* conv1_w = (const float*)d_in[8];
    const float* conv1_b = (const float*)d_in[9];
    const float* conv2_w = (const float*)d_in[10];
    const float* conv2_b = (const float*)d_in[11];
    const float* fcc_w   = (const float*)d_in[12];
    const float* fcc_b   = (const float*)d_in[13];
    const float* fc1_w   = (const float*)d_in[14];
    const float* fc1_b   = (const float*)d_in[15];
    const float* fc2_w   = (const float*)d_in[16];
    const float* fc2_b   = (const float*)d_in[17];
    const float* fc3_w   = (const float*)d_in[18];
    const float* fc3_b   = (const float*)d_in[19];
    float* out = (float*)d_out;

    // workspace layout
    unsigned short* c2bf     = (unsigned short*)d_ws;        // 16,777,216 bf16
    unsigned short* partials = c2bf + 16777216;              // 8,388,608 bf16
    float* cvec = (float*)(partials + 8388608);              // 8,192 f
    // total ~48.3 MB

    conv12_kernel<<<2048, 256, 0, stream>>>(x2, conv1_w, conv1_b,
                                            conv2_w, conv2_b, c2bf);
    fcc_mfma<<<FCC_BLOCKS, 256, 0, stream>>>(c2bf, fcc_w, partials);
    fcc_reduce<<<256, 256, 0, stream>>>(partials, fcc_b, cvec);
    head_kernel<<<64, 128, 0, stream>>>(cvec, x1, gcn1_w, gcn1_b,
                                        gcn2_w, gcn2_b, fcg_w, fcg_b,
                                        fc1_w, fc1_b, fc2_w, fc2_b,
                                        fc3_w, fc3_b, out);
}

// Round 12
// 90.793 us; speedup vs baseline: 1.0886x; 1.0886x over previous
//
#include <hip/hip_runtime.h>
#include <hip/hip_bf16.h>

// ---------------------------------------------------------------------------
// Model: [conv1+conv2 fused, MFMA] -> fcc(MFMA, 2-deep pipelined staging,
//        hoisted A) -> head(reduce + gcn + fcg + MLP)
// B=64, K(nodes)=128, N_BAND=5, HW=128, CH=16
// ---------------------------------------------------------------------------

#define IMG     16384     // 128*128
#define FCC_K   262144    // 16*128*128
#define FCC_BLOCKS 512
#define FCC_KRANGE 512    // FCC_K / FCC_BLOCKS
#define FCC_CHUNK 64      // K rows of W per LDS buffer

typedef __attribute__((ext_vector_type(8))) short bf16x8;
typedef __attribute__((ext_vector_type(4))) float f32x4;
typedef __attribute__((ext_vector_type(4))) unsigned short us4;
typedef __attribute__((ext_vector_type(8))) unsigned short us8;

// RNE float->bf16 bits (finite inputs only)
__device__ __forceinline__ unsigned short f2bf(float f) {
    unsigned u = __float_as_uint(f);
    unsigned r = (u + 0x7FFFu + ((u >> 16) & 1u)) >> 16;
    return (unsigned short)r;
}
__device__ __forceinline__ float bf2f(unsigned short b) {
    unsigned u = ((unsigned)b) << 16;
    return __uint_as_float(u);
}

// fcc LDS layout for one 64x128 chunk (shorts), transposed sWt[col][k].
// Conflict-free for BOTH ds_write_b128 staging and ds_read_b128 fragments
// (derived R7: reads slot8=(ks*4+g)^slot uniform; writes slot8=kO^slot).
__device__ __forceinline__ int fcc_swz64(int col, int k) {
    return col*64 + (k ^ ((((col >> 2) ^ col) & 7) << 3));
}

// ---------------------------------------------------------------------------
// Kernel 1: fused conv1+conv2 (3x3 SAME, relu both) -> bf16 c2. (R8 proven)
// ---------------------------------------------------------------------------
__global__ __launch_bounds__(256) void conv12_kernel(
    const float* __restrict__ x2,     // (64,128,128)
    const float* __restrict__ w1,     // (16,1,3,3)
    const float* __restrict__ b1,     // (16)
    const float* __restrict__ w2,     // (16,16,3,3)
    const float* __restrict__ b2,     // (16)
    unsigned short* __restrict__ c2bf)// (64,16,128,128) bf16
{
    __shared__ float sx2[8][130];
    __shared__ unsigned short sin[6*130*16];
    __shared__ unsigned short sB[5*512];
    __shared__ float sw1[144], sb1v[16];

    int tid = threadIdx.x;
    int blk = blockIdx.x;                     // 64 images * 32 row-groups
    int b   = blk >> 5;
    int R0  = (blk & 31) * 4;

    if (tid < 144) sw1[tid] = w1[tid];
    if (tid < 16)  sb1v[tid] = b1[tid];

    for (int idx = tid; idx < 2560; idx += 256) {
        int q   = idx >> 9;
        int rem = idx & 511;
        int l   = rem >> 3;
        int e   = rem & 7;
        int k   = (l >> 4) * 8 + e;
        int oc  = l & 15;
        int ic  = k & 15;
        int dd  = 2*q + (k >> 4);
        unsigned short bits = 0;
        if (dd < 9) bits = f2bf(w2[oc*144 + ic*9 + dd]);
        sB[idx] = bits;
    }
    if (tid < 192) {
        int rr = tid >> 5, rem = tid & 31;
        int cc = (rem < 16) ? 0 : 129;
        sin[(rr*130 + cc)*16 + (rem & 15)] = 0;
    }
    {
        const float* xb = x2 + (size_t)b * IMG;
        for (int idx = tid; idx < 8*130; idx += 256) {
            int rr = idx / 130, cc = idx - rr*130;
            int ri = R0 - 2 + rr, gj = cc - 1;
            float v = 0.f;
            if (ri >= 0 && ri < 128 && gj >= 0 && gj < 128)
                v = xb[ri*128 + gj];
            sx2[rr][cc] = v;
        }
    }
    __syncthreads();

    for (int p = tid; p < 768; p += 256) {
        int rr = p >> 7;
        int cc = p & 127;
        int ri1 = R0 - 1 + rr;
        bool valid = (ri1 >= 0 && ri1 < 128);
        float in9[3][3];
        #pragma unroll
        for (int di = 0; di < 3; ++di)
          #pragma unroll
          for (int dj = 0; dj < 3; ++dj)
              in9[di][dj] = sx2[rr + di][cc + dj];
        us8 o0, o1;
        #pragma unroll
        for (int oc = 0; oc < 16; ++oc) {
            float acc = sb1v[oc];
            #pragma unroll
            for (int di = 0; di < 3; ++di)
              #pragma unroll
              for (int dj = 0; dj < 3; ++dj)
                  acc += in9[di][dj] * sw1[oc*9 + di*3 + dj];
            unsigned short bits = valid ? f2bf(fmaxf(acc, 0.f)) : (unsigned short)0;
            if (oc < 8) o0[oc] = bits; else o1[oc - 8] = bits;
        }
        unsigned short* dst = &sin[(rr*130 + cc + 1)*16];
        *reinterpret_cast<us8*>(dst)     = o0;
        *reinterpret_cast<us8*>(dst + 8) = o1;
    }
    __syncthreads();

    int lane = tid & 63;
    int wv   = tid >> 6;
    int ln   = lane & 15;
    int g    = lane >> 4;
    int ghalf = g & 1;

    int aoff[5];
    #pragma unroll
    for (int q = 0; q < 5; ++q) {
        int dd = 2*q + (g >> 1);
        if (dd > 8) dd = 8;
        int di = dd / 3, dj = dd % 3;
        aoff[q] = ((wv + di)*130 + ln + dj)*16 + ghalf*8;
    }

    bf16x8 bf[5];
    #pragma unroll
    for (int q = 0; q < 5; ++q)
        bf[q] = *reinterpret_cast<const bf16x8*>(&sB[q*512 + lane*8]);

    float bias_oc = b2[ln];
    int r = R0 + wv;
    unsigned short* outbase = c2bf + ((size_t)b*16 + ln)*IMG + r*128;

    #pragma unroll
    for (int t = 0; t < 8; ++t) {
        f32x4 acc = {0.f, 0.f, 0.f, 0.f};
        #pragma unroll
        for (int q = 0; q < 5; ++q) {
            bf16x8 a = *reinterpret_cast<const bf16x8*>(&sin[aoff[q] + t*256]);
            acc = __builtin_amdgcn_mfma_f32_16x16x32_bf16(a, bf[q], acc, 0, 0, 0);
        }
        int pc = t*16 + g*4;
        us4 pk;
        #pragma unroll
        for (int reg = 0; reg < 4; ++reg)
            pk[reg] = f2bf(fmaxf(acc[reg] + bias_oc, 0.f));
        *reinterpret_cast<us4*>(&outbase[pc]) = pk;
    }
}

// ---------------------------------------------------------------------------
// Kernel 2: fcc split-K partials, bf16 MFMA. 512 blocks x K-slice 512.
// All 16 A-fragments hoisted to registers in the prologue (af[i]=arow+i*32,
// static). W staged via 2-deep register prefetch (rows_a/rows_b) into a
// double-buffered LDS: each chunk's loads are issued ~2 compute phases + 1
// write phase before their vmcnt wait. Chunk 2d -> buf0, 2d+1 -> buf1.
// ---------------------------------------------------------------------------
#define STAGE_LOAD(ROWS, CI)                                                  \
    {                                                                         \
        const float* Wc_ = Wb + (size_t)(CI) * FCC_CHUNK * 128;               \
        _Pragma("unroll")                                                     \
        for (int r = 0; r < 8; ++r)                                           \
            ROWS[r] = *reinterpret_cast<const float4*>(                       \
                Wc_ + (size_t)(kO*8 + r)*128 + col0);                         \
    }

#define STAGE_WRITE(ROWS, BUF)                                                \
    {                                                                         \
        us8 vc0, vc1, vc2, vc3;                                               \
        _Pragma("unroll")                                                     \
        for (int r = 0; r < 8; ++r) {                                         \
            vc0[r] = f2bf(ROWS[r].x); vc1[r] = f2bf(ROWS[r].y);               \
            vc2[r] = f2bf(ROWS[r].z); vc3[r] = f2bf(ROWS[r].w);               \
        }                                                                     \
        *reinterpret_cast<us8*>(&(BUF)[fcc_swz64(col0+0, kO*8)]) = vc0;       \
        *reinterpret_cast<us8*>(&(BUF)[fcc_swz64(col0+1, kO*8)]) = vc1;       \
        *reinterpret_cast<us8*>(&(BUF)[fcc_swz64(col0+2, kO*8)]) = vc2;       \
        *reinterpret_cast<us8*>(&(BUF)[fcc_swz64(col0+3, kO*8)]) = vc3;       \
    }

#define COMPUTE_CHUNK(BUF, AF0, AF1)                                          \
    {                                                                         \
        _Pragma("unroll")                                                     \
        for (int j = 0; j < 8; ++j) {                                         \
            bf16x8 bfrag = *reinterpret_cast<const bf16x8*>(                  \
                &(BUF)[fcc_swz64(j*16 + ln, g*8)]);                           \
            acc[j] = __builtin_amdgcn_mfma_f32_16x16x32_bf16(AF0, bfrag, acc[j], 0, 0, 0); \
        }                                                                     \
        _Pragma("unroll")                                                     \
        for (int j = 0; j < 8; ++j) {                                         \
            bf16x8 bfrag = *reinterpret_cast<const bf16x8*>(                  \
                &(BUF)[fcc_swz64(j*16 + ln, 32 + g*8)]);                      \
            acc[j] = __builtin_amdgcn_mfma_f32_16x16x32_bf16(AF1, bfrag, acc[j], 0, 0, 0); \
        }                                                                     \
    }

__global__ __launch_bounds__(256, 2) void fcc_mfma(
    const unsigned short* __restrict__ c2bf, // (64, 262144) bf16 row-major
    const float* __restrict__ W,             // (262144, 128) fp32
    unsigned short* __restrict__ partials)   // (512, 64*128) bf16
{
    __shared__ unsigned short sWt[2][FCC_CHUNK*128];  // 2 x 16 KB

    int tid  = threadIdx.x;
    int blk  = blockIdx.x;
    int k0   = blk * FCC_KRANGE;
    int lane = tid & 63, wv = tid >> 6;
    int ln   = lane & 15, g = lane >> 4;
    int q    = tid & 31;      // staging col-quad (cols 4q..4q+3)
    int kO   = tid >> 5;      // staging k-octet 0..7
    int col0 = q*4;

    f32x4 acc[8];
    #pragma unroll
    for (int j = 0; j < 8; ++j) acc[j] = (f32x4){0.f,0.f,0.f,0.f};

    const float* Wb = W + (size_t)k0 * 128;
    const unsigned short* arow = c2bf + (size_t)(16*wv + ln)*FCC_K + k0 + g*8;

    // ---- prologue: hoist ALL 16 A-fragments (af[i] covers k=i*32..i*32+31)
    bf16x8 af[16];
    #pragma unroll
    for (int i = 0; i < 16; ++i)
        af[i] = *reinterpret_cast<const bf16x8*>(arow + i*32);

    float4 rows_a[8], rows_b[8];
    STAGE_LOAD(rows_a, 0)             // chunk 0
    STAGE_LOAD(rows_b, 1)             // chunk 1
    STAGE_WRITE(rows_a, sWt[0])       // waits only rows_a's loads
    __syncthreads();

    // ---- main: 4 double-iterations, chunks 2d (buf0) and 2d+1 (buf1) ----
    #pragma unroll
    for (int d = 0; d < 4; ++d) {
        if (d < 3) STAGE_LOAD(rows_a, 2*d + 2)       // reuse rows_a regs
        COMPUTE_CHUNK(sWt[0], af[4*d + 0], af[4*d + 1])
        __syncthreads();
        STAGE_WRITE(rows_b, sWt[1])                  // chunk 2d+1 -> buf1
        __syncthreads();
        if (d < 3) STAGE_LOAD(rows_b, 2*d + 3)
        COMPUTE_CHUNK(sWt[1], af[4*d + 2], af[4*d + 3])
        __syncthreads();
        if (d < 3) {
            STAGE_WRITE(rows_a, sWt[0])              // chunk 2d+2 -> buf0
            __syncthreads();
        }
    }

    unsigned short* p = partials + (size_t)blk * 8192;
    #pragma unroll
    for (int j = 0; j < 8; ++j)
      #pragma unroll
      for (int reg = 0; reg < 4; ++reg) {
          int m = 16*wv + g*4 + reg;
          p[m*128 + j*16 + ln] = f2bf(acc[j][reg]);
      }
}

// ---------------------------------------------------------------------------
// Kernel 3: head — 4-way reduce of bf16 partials + gcn chain + fcg + MLP.
// One block per batch row (64 blocks x 512).
// ---------------------------------------------------------------------------
__global__ __launch_bounds__(512) void head_kernel(
    const unsigned short* __restrict__ partials, // (512, 8192) bf16
    const float* __restrict__ fccb,     // (128)
    const float* __restrict__ x1,       // (8192,5)
    const float* __restrict__ gW1, const float* __restrict__ gb1,
    const float* __restrict__ gW2, const float* __restrict__ gb2,
    const float* __restrict__ fcgW, const float* __restrict__ fcgb,
    const float* __restrict__ w1, const float* __restrict__ bb1,
    const float* __restrict__ w2, const float* __restrict__ bb2,
    const float* __restrict__ w3, const float* __restrict__ bb3,
    float* __restrict__ out)
{
    __shared__ float sred[4][128];
    __shared__ float sx[256], sh[128], s2[64], sh2[128];
    __shared__ float sW1[50], sb1s[10], sW2s[10], smean[10];
    __shared__ float sy1[128][10];
    int b = blockIdx.x, t = threadIdx.x;
    int o = t & 127, pr = t >> 7;

    // ---- fcc partial reduce: 4-way K-split, coalesced 256-B bf16 rows ----
    {
        const unsigned short* pb = partials + (size_t)pr*8192 + (size_t)b*128 + o;
        float s = 0.f;
        #pragma unroll 8
        for (int p = 0; p < FCC_BLOCKS/4; ++p) s += bf2f(pb[(size_t)p*4*8192]);
        sred[pr][o] = s;
    }
    if (t < 50) sW1[t] = gW1[t];
    if (t >= 64 && t < 74) { sb1s[t-64] = gb1[t-64]; sW2s[t-64] = gW2[t-64]; }
    __syncthreads();

    // ---- c = relu(sum partials + fcc_b) ----
    if (t < 128)
        sx[t] = fmaxf(sred[0][t] + sred[1][t] + sred[2][t] + sred[3][t]
                      + fccb[t], 0.f);

    // ---- gcn layer 1 for this batch's 128 rows ----
    float y[10];
    if (t < 128) {
        int r = b*128 + t;
        float x[5];
        #pragma unroll
        for (int f = 0; f < 5; ++f) x[f] = x1[r*5 + f];
        #pragma unroll
        for (int oo = 0; oo < 10; ++oo) {
            float a = 0.f;
            #pragma unroll
            for (int f = 0; f < 5; ++f) a += x[f] * sW1[f*10 + oo];
            y[oo] = a;
        }
    }
    if (b == 0) {                      // block-uniform branch, barriers legal
        if (t < 128) {
            #pragma unroll
            for (int oo = 0; oo < 10; ++oo) sy1[t][oo] = y[oo];
        }
        __syncthreads();
        if (t < 10) {
            float s = 0.f;
            for (int rr = 0; rr < 128; ++rr) s += sy1[rr][t];
            smean[t] = fmaxf(s * (1.f/128.f) + sb1s[t], 0.f);
        }
        __syncthreads();
    }
    if (t < 128) {
        float h1row[10];
        if (b == 0) {
            #pragma unroll
            for (int oo = 0; oo < 10; ++oo) h1row[oo] = smean[oo];
        } else {
            #pragma unroll
            for (int oo = 0; oo < 10; ++oo) h1row[oo] = fmaxf(y[oo] + sb1s[oo], 0.f);
        }
        // layer 2 (10->1); for b==0 all rows identical so mean == value
        float y2 = 0.f;
        #pragma unroll
        for (int oo = 0; oo < 10; ++oo) y2 += h1row[oo] * sW2s[oo];
        sh2[t] = fmaxf(y2 + gb2[0], 0.f);
    }
    __syncthreads();

    // ---- fcg: g = relu(h2 @ fcgW + fcgb) -> sx[128..255] ----
    if (t < 128) {
        float acc = fcgb[t];
        #pragma unroll 8
        for (int k = 0; k < 128; ++k) acc += sh2[k] * fcgW[k*128 + t];
        sx[128 + t] = fmaxf(acc, 0.f);
    }
    __syncthreads();

    // ---- MLP head ----
    if (t < 128) {
        float acc = bb1[t];
        for (int k = 0; k < 256; ++k) acc += sx[k] * w1[k*128 + t];
        sh[t] = fmaxf(acc, 0.f);
    }
    __syncthreads();
    if (t < 64) {
        float acc = bb2[t];
        for (int k = 0; k < 128; ++k) acc += sh[k] * w2[k*64 + t];
        s2[t] = fmaxf(acc, 0.f);
    }
    __syncthreads();
    if (t < 2) {
        float acc = bb3[t];
        for (int k = 0; k < 64; ++k) acc += s2[k] * w3[k*2 + t];
        out[b*2 + t] = 1.f / (1.f + __expf(-acc));
    }
}

// ---------------------------------------------------------------------------
extern "C" void kernel_launch(void* const* d_in, const int* in_sizes, int n_in,
                              void* d_out, int out_size, void* d_ws, size_t ws_size,
                              hipStream_t stream)
{
    const float* x1      = (const float*)d_in[0];
    const float* x2      = (const float*)d_in[1];
    const float* gcn1_w  = (const float*)d_in[2];
    const float* gcn1_b  = (const float*)d_in[3];
    const float* gcn2_w  = (const float*)d_in[4];
    const float* gcn2_b  = (const float*)d_in[5];
    const float* fcg_w   = (const float*)d_in[6];
    const float* fcg_b   = (const float*)d_in[7];
    const float* conv1_w = (const float*)d_in[8];
    const float* conv1_b = (const float*)d_in[9];
    const float* conv2_w = (const float*)d_in[10];
    const float* conv2_b = (const float*)d_in[11];
    const float* fcc_w   = (const float*)d_in[12];
    const float* fcc_b   = (const float*)d_in[13];
    const float* fc1_w   = (const float*)d_in[14];
    const float* fc1_b   = (const float*)d_in[15];
    const float* fc2_w   = (const float*)d_in[16];
    const float* fc2_b   = (const float*)d_in[17];
    const float* fc3_w   = (const float*)d_in[18];
    const float* fc3_b   = (const float*)d_in[19];
    float* out = (float*)d_out;

    // workspace layout
    unsigned short* c2bf     = (unsigned short*)d_ws;        // 16,777,216 bf16
    unsigned short* partials = c2bf + 16777216;              // 4,194,304 bf16
    // total ~40 MB

    conv12_kernel<<<2048, 256, 0, stream>>>(x2, conv1_w, conv1_b,
                                            conv2_w, conv2_b, c2bf);
    fcc_mfma<<<FCC_BLOCKS, 256, 0, stream>>>(c2bf, fcc_w, partials);
    head_kernel<<<64, 512, 0, stream>>>(partials, fcc_b,
                                        x1, gcn1_w, gcn1_b, gcn2_w, gcn2_b,
                                        fcg_w, fcg_b,
                                        fc1_w, fc1_b, fc2_w, fc2_b,
                                        fc3_w, fc3_b, out);
}